// Round 4
// baseline (328.687 us; speedup 1.0000x reference)
//
#include <hip/hip_runtime.h>
#include <math.h>

namespace {
constexpr int KF  = 1152;   // padded feature dim (1120 used + 32 zeros)
constexpr int RPB = 4;      // rows per k_feat block
}

typedef __bf16 v8bf __attribute__((ext_vector_type(8)));
typedef float  v4f  __attribute__((ext_vector_type(4)));

__device__ __forceinline__ unsigned short f2bf(float f) {
    union { float f; unsigned u; } v; v.f = f;
    unsigned r = v.u + 0x7FFFu + ((v.u >> 16) & 1u);
    return (unsigned short)(r >> 16);
}

__device__ __forceinline__ v8bf as_v8bf(uint4 u) {
    union { uint4 u; v8bf b; } c; c.u = u; return c.b;
}

// ---------------------------------------------------------------------------
// K1: per-row feature builder. 4 rows/block, 512 threads, grid 512.
// Round-3 restructure (k_feat was ~40 of the 49 us kernel budget, latency-
// bound at 2 blocks/CU with serial stages):
//   - 512 threads/block: halves every strided stage's trip count, 16 waves/CU
//   - raw-stage: thread owns a p-PAIR (2 cols) x 4 rows; depth-2 register
//     prefetch of w2 (next jb loaded while current jb's FMAs issue)
//   - per-element accumulation order identical to prior version (bitwise)
// ---------------------------------------------------------------------------
__global__ __launch_bounds__(512, 4) void k_feat(
    const float* __restrict__ Q, const float* __restrict__ K,
    const float* __restrict__ w1, const float* __restrict__ b1,
    const float* __restrict__ w2, const float* __restrict__ b2,
    unsigned short* __restrict__ featA, unsigned short* __restrict__ featB,
    float* __restrict__ cOut)
{
    __shared__ __attribute__((aligned(16))) float x_s[RPB][32];
    __shared__ __attribute__((aligned(16))) float h_s[RPB][64];
    __shared__ __attribute__((aligned(16))) float L_s[RPB][32][36];
    __shared__ __attribute__((aligned(16))) float G_s[RPB][528];   // col-major packed
    __shared__ __attribute__((aligned(16))) float u_s[RPB][32];
    __shared__ unsigned short tri_s[528];                          // (i<<8)|j

    const int t  = threadIdx.x;
    const int g0 = blockIdx.x * RPB;

    // ---- triangular index table (once)
    for (int pr = t; pr < 528; pr += 512) {
        int j = (int)((65.0f - sqrtf(4225.0f - 8.0f * (float)pr)) * 0.5f);
        while (j > 0 && j * (65 - j) / 2 > pr) --j;
        while ((j + 1) * (64 - j) / 2 <= pr) ++j;
        int i = j + (pr - j * (65 - j) / 2);
        tri_s[pr] = (unsigned short)((i << 8) | j);
    }
    // ---- load x
    if (t < RPB * 32) {
        int r = t >> 5, i = t & 31;
        int g = g0 + r;
        const float* src = (g < 1024) ? (Q + (size_t)g * 32)
                                      : (K + (size_t)(g - 1024) * 32);
        x_s[r][i] = src[i];
    }
    __syncthreads();

    // ---- h = silu(x @ w1 + b1): 256 outputs, threads 0..255
    if (t < RPB * 64) {
        int r = t >> 6, j = t & 63;
        float z = b1[j];
        #pragma unroll
        for (int i = 0; i < 32; ++i) z = fmaf(x_s[r][i], w1[i * 64 + j], z);
        h_s[r][j] = z / (1.0f + __expf(-z));
    }
    __syncthreads();

    // ---- raw = h @ w2 + b2 -> L.  Thread t owns p-pair [2t,2t+2), all 4 rows.
    // Depth-2 register prefetch of w2: load jb+1 while jb's FMAs issue.
    {
        const int p2 = t * 2;
        float acc0[RPB], acc1[RPB];
        float2 bq = *(const float2*)&b2[p2];
        #pragma unroll
        for (int r = 0; r < RPB; ++r) { acc0[r] = bq.x; acc1[r] = bq.y; }

        float2 W[8];
        #pragma unroll
        for (int jj = 0; jj < 8; ++jj)
            W[jj] = *(const float2*)&w2[(size_t)jj * 1024 + p2];

        for (int jb = 0; jb < 8; ++jb) {
            float2 Wn[8];
            if (jb < 7) {
                #pragma unroll
                for (int jj = 0; jj < 8; ++jj)
                    Wn[jj] = *(const float2*)&w2[(size_t)((jb + 1) * 8 + jj) * 1024 + p2];
            }
            float h8[RPB][8];
            #pragma unroll
            for (int r = 0; r < RPB; ++r) {
                *(float4*)&h8[r][0] = *(const float4*)&h_s[r][jb * 8 + 0];
                *(float4*)&h8[r][4] = *(const float4*)&h_s[r][jb * 8 + 4];
            }
            #pragma unroll
            for (int jj = 0; jj < 8; ++jj) {
                #pragma unroll
                for (int r = 0; r < RPB; ++r) {
                    acc0[r] = fmaf(h8[r][jj], W[jj].x, acc0[r]);
                    acc1[r] = fmaf(h8[r][jj], W[jj].y, acc1[r]);
                }
            }
            if (jb < 7) {
                #pragma unroll
                for (int jj = 0; jj < 8; ++jj) W[jj] = Wn[jj];
            }
        }
        const int i  = p2 >> 5;
        const int j0 = p2 & 31;
        #pragma unroll
        for (int r = 0; r < RPB; ++r) {
            float lv[2];
            #pragma unroll
            for (int e = 0; e < 2; ++e) {
                int j = j0 + e;
                float raw = (e == 0) ? acc0[r] : acc1[r];
                float ex = __expf(0.4f * raw);
                float c5 = 5.0f * (ex - 1.0f) / (ex + 1.0f);   // 5*tanh(raw/5)
                float val;
                if (i < j)       val = 0.0f;
                else if (i == j) { float z = c5 + 1.0f; val = log1pf(__expf(z)) + 1e-4f; }
                else             val = c5;
                lv[e] = val;
            }
            *(float2*)&L_s[r][i][j0] = *(float2*)lv;
        }
    }
    __syncthreads();

    // ---- G = L L^T (lower triangle, packed column-major)
    for (int idx = t; idx < RPB * 528; idx += 512) {
        int r  = idx / 528;
        int pr = idx - r * 528;
        int tv = tri_s[pr];
        int i = tv >> 8, j = tv & 255;
        const float* Li = &L_s[r][i][0];
        const float* Lj = &L_s[r][j][0];
        float s = 0.0f;
        int nf = (j + 1) >> 2;
        for (int q = 0; q < nf; ++q) {
            float4 a  = *(const float4*)&Li[q * 4];
            float4 bb = *(const float4*)&Lj[q * 4];
            s += a.x * bb.x + a.y * bb.y + a.z * bb.z + a.w * bb.w;
        }
        for (int tt = nf * 4; tt <= j; ++tt) s = fmaf(Li[tt], Lj[tt], s);
        G_s[r][pr] = s;
    }
    __syncthreads();

    // ---- u = G x
    if (t < RPB * 32) {
        int r = t >> 5, i = t & 31;
        float s = 0.0f;
        #pragma unroll
        for (int j = 0; j < 32; ++j) {
            float gv = (j <= i) ? G_s[r][j * (65 - j) / 2 + i - j]
                                : G_s[r][i * (65 - i) / 2 + j - i];
            s = fmaf(gv, x_s[r][j], s);
        }
        u_s[r][i] = s;
    }
    __syncthreads();

    // ---- c = u . x
    if (t < RPB) {
        float s = 0.0f;
        #pragma unroll
        for (int i = 0; i < 32; ++i) s = fmaf(u_s[t][i], x_s[t][i], s);
        cOut[g0 + t] = s;
    }

    // ---- feature write: quads of 4 bf16, packed uint2 stores (coalesced).
    for (int idx = t; idx < RPB * (KF / 4); idx += 512) {
        int r   = idx / (KF / 4);
        int q   = idx - r * (KF / 4);
        int pos = q * 4;
        int g   = g0 + r;
        bool isA = (g < 1024);
        unsigned short* dst = isA ? (featA + (size_t)g * KF)
                                  : (featB + (size_t)(g - 1024) * KF);
        unsigned short ev[4];
        #pragma unroll
        for (int e = 0; e < 4; ++e) {
            int p = pos + e;
            float va;
            if (p < 1056) {
                int pr = (p < 528) ? p : p - 528;
                bool wantG = (p < 528) ? isA : !isA;
                int tv = tri_s[pr];
                int i = tv >> 8, j = tv & 255;
                float gv = G_s[r][pr] * ((i == j) ? 1.0f : 2.0f);
                float ov = x_s[r][i] * x_s[r][j];
                va = wantG ? gv : ov;
            } else if (p < 1088) {
                int i = p - 1056;
                va = isA ? u_s[r][i] : -2.0f * x_s[r][i];
            } else if (p < 1120) {
                int i = p - 1088;
                va = isA ? x_s[r][i] : -2.0f * u_s[r][i];
            } else {
                va = 0.0f;   // ws re-poisoned 0xAA — pad must be written
            }
            ev[e] = f2bf(va);
        }
        uint2 w;
        w.x = (unsigned)ev[0] | ((unsigned)ev[1] << 16);
        w.y = (unsigned)ev[2] | ((unsigned)ev[3] << 16);
        *(uint2*)(dst + pos) = w;
    }
}

// ---------------------------------------------------------------------------
// K2: out = sqrt(clip(0.5*(cA+cB+A.B))). In-block split-K (verified round-1
// version, unchanged): 256 threads = 4 waves per 32x32 tile; wave w owns
// K-chunk [w*288,(w+1)*288), depth-4 register prefetch, LDS reduction with
// fused epilogue. 512 blocks -> 8 waves/CU. Bijective XCD swizzle.
// ---------------------------------------------------------------------------
__global__ __launch_bounds__(256) void k_gemm(
    const unsigned short* __restrict__ featA,
    const unsigned short* __restrict__ featB,
    const float* __restrict__ cOut,
    float* __restrict__ out)
{
    __shared__ __attribute__((aligned(16))) float red[4][32][36];  // +4 pad

    const int t    = threadIdx.x;
    const int lane = t & 63;
    const int w    = t >> 6;          // wave id 0..3 = K-chunk id

    // bijective XCD swizzle over 512 blocks (512 % 8 == 0)
    const int lin = blockIdx.x;
    const int swz = (lin & 7) * 64 + (lin >> 3);
    const int m0 = (swz & 15) * 32;
    const int n0 = ((swz >> 4) & 15) * 32;
    const int b  = swz >> 8;

    const int fr = lane & 15;
    const int fq = lane >> 4;
    const int kbase = w * 288 + fq * 8;     // this wave's K-chunk start

    const unsigned short* pA0 = featA + (size_t)(b * 512 + n0 + fr) * KF + kbase;
    const unsigned short* pA1 = pA0 + (size_t)16 * KF;
    const unsigned short* pB0 = featB + (size_t)(b * 512 + m0 + fr) * KF + kbase;
    const unsigned short* pB1 = pB0 + (size_t)16 * KF;

    v4f acc00 = {0,0,0,0}, acc01 = {0,0,0,0}, acc10 = {0,0,0,0}, acc11 = {0,0,0,0};

    // depth-4 register prefetch over this wave's 9 k-steps
    uint4 bA0[4], bA1[4], bB0[4], bB1[4];
    #pragma unroll
    for (int s = 0; s < 4; ++s) {
        bA0[s] = *(const uint4*)(pA0 + s * 32);
        bA1[s] = *(const uint4*)(pA1 + s * 32);
        bB0[s] = *(const uint4*)(pB0 + s * 32);
        bB1[s] = *(const uint4*)(pB1 + s * 32);
    }

    #pragma unroll
    for (int s = 0; s < 9; ++s) {
        const int slot = s & 3;
        v8bf a0  = as_v8bf(bA0[slot]);
        v8bf a1  = as_v8bf(bA1[slot]);
        v8bf b0v = as_v8bf(bB0[slot]);
        v8bf b1v = as_v8bf(bB1[slot]);
        const int kn = s + 4;
        if (kn < 9) {
            bA0[slot] = *(const uint4*)(pA0 + kn * 32);
            bA1[slot] = *(const uint4*)(pA1 + kn * 32);
            bB0[slot] = *(const uint4*)(pB0 + kn * 32);
            bB1[slot] = *(const uint4*)(pB1 + kn * 32);
        }
        acc00 = __builtin_amdgcn_mfma_f32_16x16x32_bf16(a0, b0v, acc00, 0, 0, 0);
        acc01 = __builtin_amdgcn_mfma_f32_16x16x32_bf16(a0, b1v, acc01, 0, 0, 0);
        acc10 = __builtin_amdgcn_mfma_f32_16x16x32_bf16(a1, b0v, acc10, 0, 0, 0);
        acc11 = __builtin_amdgcn_mfma_f32_16x16x32_bf16(a1, b1v, acc11, 0, 0, 0);
    }

    // ---- deposit partial tile: D elem (lane,v): row n_l = (lane>>4)*4+v, col m_l = lane&15
    #pragma unroll
    for (int v = 0; v < 4; ++v) {
        red[w][fq * 4 + v][fr]           = acc00[v];
        red[w][fq * 4 + v][fr + 16]      = acc01[v];
        red[w][16 + fq * 4 + v][fr]      = acc10[v];
        red[w][16 + fq * 4 + v][fr + 16] = acc11[v];
    }
    __syncthreads();

    // ---- reduce 4 K-chunks + epilogue. Thread t: row n_l = t>>3, cols m_l0..+3.
    const int n_l  = t >> 3;
    const int m_l0 = (t & 7) * 4;
    float4 s0 = *(const float4*)&red[0][n_l][m_l0];
    float4 s1 = *(const float4*)&red[1][n_l][m_l0];
    float4 s2 = *(const float4*)&red[2][n_l][m_l0];
    float4 s3 = *(const float4*)&red[3][n_l][m_l0];

    const int   n_g = n0 + n_l;
    const float cA  = cOut[b * 512 + n_g];
    const float4 cB = *(const float4*)&cOut[1024 + b * 512 + m0 + m_l0];

    float4 res;
    {
        float tot[4] = { s0.x + s1.x + s2.x + s3.x,
                         s0.y + s1.y + s2.y + s3.y,
                         s0.z + s1.z + s2.z + s3.z,
                         s0.w + s1.w + s2.w + s3.w };
        const float cb[4] = { cB.x, cB.y, cB.z, cB.w };
        float* rp = (float*)&res;
        #pragma unroll
        for (int e = 0; e < 4; ++e) {
            float dsq = 0.5f * (tot[e] + cA + cb[e]);
            dsq = fminf(fmaxf(dsq, 1e-6f), 1e6f);
            rp[e] = sqrtf(dsq);
        }
    }
    *(float4*)&out[((size_t)(b * 512 + n_g)) * 512 + m0 + m_l0] = res;
}

// ---------------------------------------------------------------------------
extern "C" void kernel_launch(void* const* d_in, const int* in_sizes, int n_in,
                              void* d_out, int out_size, void* d_ws, size_t ws_size,
                              hipStream_t stream)
{
    const float* Q  = (const float*)d_in[0];
    const float* K  = (const float*)d_in[1];
    const float* w1 = (const float*)d_in[2];
    const float* b1 = (const float*)d_in[3];
    const float* w2 = (const float*)d_in[4];
    const float* b2 = (const float*)d_in[5];
    float* out = (float*)d_out;

    unsigned short* featA = (unsigned short*)d_ws;            // [1024][1152] bf16
    unsigned short* featB = featA + (size_t)1024 * KF;        // [1024][1152] bf16
    float* cOut = (float*)(featB + (size_t)1024 * KF);        // [2048] fp32

    k_feat<<<dim3(2048 / RPB), dim3(512), 0, stream>>>(Q, K, w1, b1, w2, b2, featA, featB, cOut);
    k_gemm<<<dim3(512), dim3(256), 0, stream>>>(featA, featB, cOut, out);
}

// Round 5
// 142.358 us; speedup vs baseline: 2.3089x; 2.3089x over previous
//
#include <hip/hip_runtime.h>
#include <math.h>

namespace {
constexpr int KF  = 1152;   // padded feature dim (1120 used + 32 zeros)
constexpr int RPB = 2;      // rows per k_feat block (4->2: grid 1024, 4 blk/CU)
}

typedef __bf16 v8bf __attribute__((ext_vector_type(8)));
typedef float  v4f  __attribute__((ext_vector_type(4)));

__device__ __forceinline__ unsigned short f2bf(float f) {
    union { float f; unsigned u; } v; v.f = f;
    unsigned r = v.u + 0x7FFFu + ((v.u >> 16) & 1u);
    return (unsigned short)(r >> 16);
}

__device__ __forceinline__ v8bf as_v8bf(uint4 u) {
    union { uint4 u; v8bf b; } c; c.u = u; return c.b;
}

// ---------------------------------------------------------------------------
// K1: per-row feature builder. Round-5: exact round-1 structure (256 thr,
// float4 w2 loads, natural VGPR allocation — round-4's forced launch_bounds
// caused 700 MB of scratch spills, VGPR capped at 64) with RPB 4->2:
// grid 1024 = 4 blocks/CU = 2x wave pool for latency hiding. Register
// working set halves (acc[2][4], h8[2][8]). w2 L2 traffic doubles (~256 MB,
// ~7.5 us at L2 BW) — cheap vs the latency win.
// ---------------------------------------------------------------------------
__global__ __launch_bounds__(256) void k_feat(
    const float* __restrict__ Q, const float* __restrict__ K,
    const float* __restrict__ w1, const float* __restrict__ b1,
    const float* __restrict__ w2, const float* __restrict__ b2,
    unsigned short* __restrict__ featA, unsigned short* __restrict__ featB,
    float* __restrict__ cOut)
{
    __shared__ __attribute__((aligned(16))) float x_s[RPB][32];
    __shared__ __attribute__((aligned(16))) float h_s[RPB][64];
    __shared__ __attribute__((aligned(16))) float L_s[RPB][32][36];
    __shared__ __attribute__((aligned(16))) float G_s[RPB][528];   // col-major packed
    __shared__ __attribute__((aligned(16))) float u_s[RPB][32];
    __shared__ unsigned short tri_s[528];                          // (i<<8)|j

    const int t  = threadIdx.x;
    const int g0 = blockIdx.x * RPB;

    // ---- triangular index table (once)
    for (int pr = t; pr < 528; pr += 256) {
        int j = (int)((65.0f - sqrtf(4225.0f - 8.0f * (float)pr)) * 0.5f);
        while (j > 0 && j * (65 - j) / 2 > pr) --j;
        while ((j + 1) * (64 - j) / 2 <= pr) ++j;
        int i = j + (pr - j * (65 - j) / 2);
        tri_s[pr] = (unsigned short)((i << 8) | j);
    }
    // ---- load x
    if (t < RPB * 32) {
        int r = t >> 5, i = t & 31;
        int g = g0 + r;
        const float* src = (g < 1024) ? (Q + (size_t)g * 32)
                                      : (K + (size_t)(g - 1024) * 32);
        x_s[r][i] = src[i];
    }
    __syncthreads();

    // ---- h = silu(x @ w1 + b1): RPB*64 outputs, 1/thread
    if (t < RPB * 64) {
        int r = t >> 6, j = t & 63;
        float z = b1[j];
        #pragma unroll
        for (int i = 0; i < 32; ++i) z = fmaf(x_s[r][i], w1[i * 64 + j], z);
        h_s[r][j] = z / (1.0f + __expf(-z));
    }
    __syncthreads();

    // ---- raw = h @ w2 + b2 -> L.  Thread t owns p-quad [4t,4t+4), all RPB rows.
    {
        const int p4 = t * 4;
        float acc[RPB][4];
        float4 bq = *(const float4*)&b2[p4];
        #pragma unroll
        for (int r = 0; r < RPB; ++r) {
            acc[r][0] = bq.x; acc[r][1] = bq.y; acc[r][2] = bq.z; acc[r][3] = bq.w;
        }
        for (int jb = 0; jb < 8; ++jb) {
            float h8[RPB][8];
            #pragma unroll
            for (int r = 0; r < RPB; ++r) {
                *(float4*)&h8[r][0] = *(const float4*)&h_s[r][jb * 8 + 0];
                *(float4*)&h8[r][4] = *(const float4*)&h_s[r][jb * 8 + 4];
            }
            #pragma unroll
            for (int jj = 0; jj < 8; ++jj) {
                float4 w = *(const float4*)&w2[(size_t)(jb * 8 + jj) * 1024 + p4];
                #pragma unroll
                for (int r = 0; r < RPB; ++r) {
                    acc[r][0] = fmaf(h8[r][jj], w.x, acc[r][0]);
                    acc[r][1] = fmaf(h8[r][jj], w.y, acc[r][1]);
                    acc[r][2] = fmaf(h8[r][jj], w.z, acc[r][2]);
                    acc[r][3] = fmaf(h8[r][jj], w.w, acc[r][3]);
                }
            }
        }
        const int i  = p4 >> 5;
        const int j0 = p4 & 31;
        #pragma unroll
        for (int r = 0; r < RPB; ++r) {
            float4 lv;
            float* lvp = (float*)&lv;
            #pragma unroll
            for (int e = 0; e < 4; ++e) {
                int j = j0 + e;
                float raw = acc[r][e];
                float ex = __expf(0.4f * raw);
                float c5 = 5.0f * (ex - 1.0f) / (ex + 1.0f);   // 5*tanh(raw/5)
                float val;
                if (i < j)       val = 0.0f;
                else if (i == j) { float z = c5 + 1.0f; val = log1pf(__expf(z)) + 1e-4f; }
                else             val = c5;
                lvp[e] = val;
            }
            *(float4*)&L_s[r][i][j0] = lv;
        }
    }
    __syncthreads();

    // ---- G = L L^T (lower triangle, packed column-major)
    for (int idx = t; idx < RPB * 528; idx += 256) {
        int r  = idx / 528;
        int pr = idx - r * 528;
        int tv = tri_s[pr];
        int i = tv >> 8, j = tv & 255;
        const float* Li = &L_s[r][i][0];
        const float* Lj = &L_s[r][j][0];
        float s = 0.0f;
        int nf = (j + 1) >> 2;
        for (int q = 0; q < nf; ++q) {
            float4 a  = *(const float4*)&Li[q * 4];
            float4 bb = *(const float4*)&Lj[q * 4];
            s += a.x * bb.x + a.y * bb.y + a.z * bb.z + a.w * bb.w;
        }
        for (int tt = nf * 4; tt <= j; ++tt) s = fmaf(Li[tt], Lj[tt], s);
        G_s[r][pr] = s;
    }
    __syncthreads();

    // ---- u = G x
    if (t < RPB * 32) {
        int r = t >> 5, i = t & 31;
        float s = 0.0f;
        #pragma unroll
        for (int j = 0; j < 32; ++j) {
            float gv = (j <= i) ? G_s[r][j * (65 - j) / 2 + i - j]
                                : G_s[r][i * (65 - i) / 2 + j - i];
            s = fmaf(gv, x_s[r][j], s);
        }
        u_s[r][i] = s;
    }
    __syncthreads();

    // ---- c = u . x
    if (t < RPB) {
        float s = 0.0f;
        #pragma unroll
        for (int i = 0; i < 32; ++i) s = fmaf(u_s[t][i], x_s[t][i], s);
        cOut[g0 + t] = s;
    }

    // ---- feature write: quads of 4 bf16, packed uint2 stores (coalesced).
    // All region boundaries (528/1056/1088/1120/1152) are multiples of 4.
    for (int idx = t; idx < RPB * (KF / 4); idx += 256) {
        int r   = idx / (KF / 4);
        int q   = idx - r * (KF / 4);
        int pos = q * 4;
        int g   = g0 + r;
        bool isA = (g < 1024);
        unsigned short* dst = isA ? (featA + (size_t)g * KF)
                                  : (featB + (size_t)(g - 1024) * KF);
        unsigned short ev[4];
        #pragma unroll
        for (int e = 0; e < 4; ++e) {
            int p = pos + e;
            float va;
            if (p < 1056) {
                int pr = (p < 528) ? p : p - 528;
                bool wantG = (p < 528) ? isA : !isA;
                int tv = tri_s[pr];
                int i = tv >> 8, j = tv & 255;
                float gv = G_s[r][pr] * ((i == j) ? 1.0f : 2.0f);
                float ov = x_s[r][i] * x_s[r][j];
                va = wantG ? gv : ov;
            } else if (p < 1088) {
                int i = p - 1056;
                va = isA ? u_s[r][i] : -2.0f * x_s[r][i];
            } else if (p < 1120) {
                int i = p - 1088;
                va = isA ? x_s[r][i] : -2.0f * u_s[r][i];
            } else {
                va = 0.0f;   // ws re-poisoned 0xAA — pad must be written
            }
            ev[e] = f2bf(va);
        }
        uint2 w;
        w.x = (unsigned)ev[0] | ((unsigned)ev[1] << 16);
        w.y = (unsigned)ev[2] | ((unsigned)ev[3] << 16);
        *(uint2*)(dst + pos) = w;
    }
}

// ---------------------------------------------------------------------------
// K2: out = sqrt(clip(0.5*(cA+cB+A.B))). In-block split-K (verified round-1
// version, unchanged): 256 threads = 4 waves per 32x32 tile; wave w owns
// K-chunk [w*288,(w+1)*288), depth-4 register prefetch, LDS reduction with
// fused epilogue. 512 blocks -> 8 waves/CU. Bijective XCD swizzle.
// ---------------------------------------------------------------------------
__global__ __launch_bounds__(256) void k_gemm(
    const unsigned short* __restrict__ featA,
    const unsigned short* __restrict__ featB,
    const float* __restrict__ cOut,
    float* __restrict__ out)
{
    __shared__ __attribute__((aligned(16))) float red[4][32][36];  // +4 pad

    const int t    = threadIdx.x;
    const int lane = t & 63;
    const int w    = t >> 6;          // wave id 0..3 = K-chunk id

    // bijective XCD swizzle over 512 blocks (512 % 8 == 0)
    const int lin = blockIdx.x;
    const int swz = (lin & 7) * 64 + (lin >> 3);
    const int m0 = (swz & 15) * 32;
    const int n0 = ((swz >> 4) & 15) * 32;
    const int b  = swz >> 8;

    const int fr = lane & 15;
    const int fq = lane >> 4;
    const int kbase = w * 288 + fq * 8;     // this wave's K-chunk start

    const unsigned short* pA0 = featA + (size_t)(b * 512 + n0 + fr) * KF + kbase;
    const unsigned short* pA1 = pA0 + (size_t)16 * KF;
    const unsigned short* pB0 = featB + (size_t)(b * 512 + m0 + fr) * KF + kbase;
    const unsigned short* pB1 = pB0 + (size_t)16 * KF;

    v4f acc00 = {0,0,0,0}, acc01 = {0,0,0,0}, acc10 = {0,0,0,0}, acc11 = {0,0,0,0};

    // depth-4 register prefetch over this wave's 9 k-steps
    uint4 bA0[4], bA1[4], bB0[4], bB1[4];
    #pragma unroll
    for (int s = 0; s < 4; ++s) {
        bA0[s] = *(const uint4*)(pA0 + s * 32);
        bA1[s] = *(const uint4*)(pA1 + s * 32);
        bB0[s] = *(const uint4*)(pB0 + s * 32);
        bB1[s] = *(const uint4*)(pB1 + s * 32);
    }

    #pragma unroll
    for (int s = 0; s < 9; ++s) {
        const int slot = s & 3;
        v8bf a0  = as_v8bf(bA0[slot]);
        v8bf a1  = as_v8bf(bA1[slot]);
        v8bf b0v = as_v8bf(bB0[slot]);
        v8bf b1v = as_v8bf(bB1[slot]);
        const int kn = s + 4;
        if (kn < 9) {
            bA0[slot] = *(const uint4*)(pA0 + kn * 32);
            bA1[slot] = *(const uint4*)(pA1 + kn * 32);
            bB0[slot] = *(const uint4*)(pB0 + kn * 32);
            bB1[slot] = *(const uint4*)(pB1 + kn * 32);
        }
        acc00 = __builtin_amdgcn_mfma_f32_16x16x32_bf16(a0, b0v, acc00, 0, 0, 0);
        acc01 = __builtin_amdgcn_mfma_f32_16x16x32_bf16(a0, b1v, acc01, 0, 0, 0);
        acc10 = __builtin_amdgcn_mfma_f32_16x16x32_bf16(a1, b0v, acc10, 0, 0, 0);
        acc11 = __builtin_amdgcn_mfma_f32_16x16x32_bf16(a1, b1v, acc11, 0, 0, 0);
    }

    // ---- deposit partial tile: D elem (lane,v): row n_l = (lane>>4)*4+v, col m_l = lane&15
    #pragma unroll
    for (int v = 0; v < 4; ++v) {
        red[w][fq * 4 + v][fr]           = acc00[v];
        red[w][fq * 4 + v][fr + 16]      = acc01[v];
        red[w][16 + fq * 4 + v][fr]      = acc10[v];
        red[w][16 + fq * 4 + v][fr + 16] = acc11[v];
    }
    __syncthreads();

    // ---- reduce 4 K-chunks + epilogue. Thread t: row n_l = t>>3, cols m_l0..+3.
    const int n_l  = t >> 3;
    const int m_l0 = (t & 7) * 4;
    float4 s0 = *(const float4*)&red[0][n_l][m_l0];
    float4 s1 = *(const float4*)&red[1][n_l][m_l0];
    float4 s2 = *(const float4*)&red[2][n_l][m_l0];
    float4 s3 = *(const float4*)&red[3][n_l][m_l0];

    const int   n_g = n0 + n_l;
    const float cA  = cOut[b * 512 + n_g];
    const float4 cB = *(const float4*)&cOut[1024 + b * 512 + m0 + m_l0];

    float4 res;
    {
        float tot[4] = { s0.x + s1.x + s2.x + s3.x,
                         s0.y + s1.y + s2.y + s3.y,
                         s0.z + s1.z + s2.z + s3.z,
                         s0.w + s1.w + s2.w + s3.w };
        const float cb[4] = { cB.x, cB.y, cB.z, cB.w };
        float* rp = (float*)&res;
        #pragma unroll
        for (int e = 0; e < 4; ++e) {
            float dsq = 0.5f * (tot[e] + cA + cb[e]);
            dsq = fminf(fmaxf(dsq, 1e-6f), 1e6f);
            rp[e] = sqrtf(dsq);
        }
    }
    *(float4*)&out[((size_t)(b * 512 + n_g)) * 512 + m0 + m_l0] = res;
}

// ---------------------------------------------------------------------------
extern "C" void kernel_launch(void* const* d_in, const int* in_sizes, int n_in,
                              void* d_out, int out_size, void* d_ws, size_t ws_size,
                              hipStream_t stream)
{
    const float* Q  = (const float*)d_in[0];
    const float* K  = (const float*)d_in[1];
    const float* w1 = (const float*)d_in[2];
    const float* b1 = (const float*)d_in[3];
    const float* w2 = (const float*)d_in[4];
    const float* b2 = (const float*)d_in[5];
    float* out = (float*)d_out;

    unsigned short* featA = (unsigned short*)d_ws;            // [1024][1152] bf16
    unsigned short* featB = featA + (size_t)1024 * KF;        // [1024][1152] bf16
    float* cOut = (float*)(featB + (size_t)1024 * KF);        // [2048] fp32

    k_feat<<<dim3(2048 / RPB), dim3(256), 0, stream>>>(Q, K, w1, b1, w2, b2, featA, featB, cOut);
    k_gemm<<<dim3(512), dim3(256), 0, stream>>>(featA, featB, cOut, out);
}

// Round 6
// 106.347 us; speedup vs baseline: 3.0907x; 1.3386x over previous
//
#include <hip/hip_runtime.h>
#include <math.h>

namespace {
constexpr int KF  = 1152;   // padded feature dim (1120 used + 32 zeros)
constexpr int RPB = 4;      // rows per k_feat block (grid 512)
}

typedef __bf16 v8bf __attribute__((ext_vector_type(8)));
typedef float  v4f  __attribute__((ext_vector_type(4)));

__device__ __forceinline__ unsigned short f2bf(float f) {
    union { float f; unsigned u; } v; v.f = f;
    unsigned r = v.u + 0x7FFFu + ((v.u >> 16) & 1u);
    return (unsigned short)(r >> 16);
}

__device__ __forceinline__ v8bf as_v8bf(uint4 u) {
    union { uint4 u; v8bf b; } c; c.u = u; return c.b;
}

// async global->LDS, 16B per lane (wave-uniform LDS base + lane*16; global
// source address is per-lane). Size must be a literal 16.
__device__ __forceinline__ void g2l16(const float* g, float* l) {
    __builtin_amdgcn_global_load_lds(
        (const __attribute__((address_space(1))) void*)g,
        (__attribute__((address_space(3))) void*)l,
        16, 0, 0);
}

// ---------------------------------------------------------------------------
// K1: per-row feature builder. 4 rows/block, 256 threads, grid 512.
// Round-6: the h@w2 stage was L2-LATENCY-bound with blocking VGPR loads
// (~8 outstanding/wave -> ~45us at RPB=4, ~105us at RPB=2; FETCH_SIZE 1.4MB
// proved w2 is L2-resident). Replace with global_load_lds width-16 DMA of
// w2 in 4-row (16KB) chunks, double-buffered in LDS: fire-and-forget queue
// turns the stall model from latency into L2 BW (~4us/CU for 512KB).
// Chunk-0 DMA issued at kernel entry, hidden under tri/x/h stages.
// Per-element FMA order (rows 0..63 ascending) identical to round-1 ->
// bitwise-identical results.
// ---------------------------------------------------------------------------
__global__ __launch_bounds__(256) void k_feat(
    const float* __restrict__ Q, const float* __restrict__ K,
    const float* __restrict__ w1, const float* __restrict__ b1,
    const float* __restrict__ w2, const float* __restrict__ b2,
    unsigned short* __restrict__ featA, unsigned short* __restrict__ featB,
    float* __restrict__ cOut)
{
    __shared__ __attribute__((aligned(16))) float x_s[RPB][32];
    __shared__ __attribute__((aligned(16))) float h_s[RPB][64];
    __shared__ __attribute__((aligned(16))) float L_s[RPB][32][36];
    __shared__ __attribute__((aligned(16))) float G_s[RPB][528];   // col-major packed
    __shared__ __attribute__((aligned(16))) float u_s[RPB][32];
    __shared__ __attribute__((aligned(16))) float wbuf[2][4 * 1024]; // w2 4-row chunks, dbuf (32KB)
    __shared__ unsigned short tri_s[528];                          // (i<<8)|j

    const int t    = threadIdx.x;
    const int lane = t & 63;
    const int wv   = t >> 6;
    const int g0   = blockIdx.x * RPB;

    // ---- issue DMA for w2 chunk 0 immediately (rows 0..3, 16 instrs: 4/wave)
    {
        #pragma unroll
        for (int k = 0; k < 4; ++k) {
            int q = wv * 4 + k;                       // 0..15, 1KB segments
            g2l16(w2 + (size_t)q * 256 + lane * 4, &wbuf[0][q * 256]);
        }
    }

    // ---- triangular index table (once)
    for (int pr = t; pr < 528; pr += 256) {
        int j = (int)((65.0f - sqrtf(4225.0f - 8.0f * (float)pr)) * 0.5f);
        while (j > 0 && j * (65 - j) / 2 > pr) --j;
        while ((j + 1) * (64 - j) / 2 <= pr) ++j;
        int i = j + (pr - j * (65 - j) / 2);
        tri_s[pr] = (unsigned short)((i << 8) | j);
    }
    // ---- load x
    if (t < RPB * 32) {
        int r = t >> 5, i = t & 31;
        int g = g0 + r;
        const float* src = (g < 1024) ? (Q + (size_t)g * 32)
                                      : (K + (size_t)(g - 1024) * 32);
        x_s[r][i] = src[i];
    }
    __syncthreads();

    // ---- h = silu(x @ w1 + b1): 256 outputs, 1/thread
    {
        int r = t >> 6, j = t & 63;
        float z = b1[j];
        #pragma unroll
        for (int i = 0; i < 32; ++i) z = fmaf(x_s[r][i], w1[i * 64 + j], z);
        h_s[r][j] = z / (1.0f + __expf(-z));
    }
    __syncthreads();   // also drains vmcnt -> wbuf[0] ready

    // ---- raw = h @ w2 + b2 -> L.  Thread t owns p-quad [4t,4t+4), all 4 rows.
    // 16 chunks of 4 w2-rows, double-buffered DMA staging.
    {
        const int p4 = t * 4;
        float acc[RPB][4];
        float4 bq = *(const float4*)&b2[p4];
        #pragma unroll
        for (int r = 0; r < RPB; ++r) {
            acc[r][0] = bq.x; acc[r][1] = bq.y; acc[r][2] = bq.z; acc[r][3] = bq.w;
        }
        for (int c = 0; c < 16; ++c) {
            const int buf = c & 1;
            if (c < 15) {   // issue DMA for chunk c+1 into the other buffer
                #pragma unroll
                for (int k = 0; k < 4; ++k) {
                    int q = wv * 4 + k;
                    g2l16(w2 + (size_t)(c + 1) * 4096 + q * 256 + lane * 4,
                          &wbuf[buf ^ 1][q * 256]);
                }
            }
            // h values for the 4 rows of this chunk (LDS broadcast reads)
            float4 h4[RPB];
            #pragma unroll
            for (int r = 0; r < RPB; ++r)
                h4[r] = *(const float4*)&h_s[r][c * 4];
            const float* hp[RPB];
            #pragma unroll
            for (int jr = 0; jr < 4; ++jr) {
                float4 wq = *(const float4*)&wbuf[buf][jr * 1024 + p4];
                #pragma unroll
                for (int r = 0; r < RPB; ++r) {
                    float hv = ((const float*)&h4[r])[jr];
                    acc[r][0] = fmaf(hv, wq.x, acc[r][0]);
                    acc[r][1] = fmaf(hv, wq.y, acc[r][1]);
                    acc[r][2] = fmaf(hv, wq.z, acc[r][2]);
                    acc[r][3] = fmaf(hv, wq.w, acc[r][3]);
                }
            }
            (void)hp;
            if (c < 15) __syncthreads();   // drains vmcnt (chunk c+1 ready) + guards buffer reuse
        }
        const int i  = p4 >> 5;
        const int j0 = p4 & 31;
        #pragma unroll
        for (int r = 0; r < RPB; ++r) {
            float4 lv;
            float* lvp = (float*)&lv;
            #pragma unroll
            for (int e = 0; e < 4; ++e) {
                int j = j0 + e;
                float raw = acc[r][e];
                float ex = __expf(0.4f * raw);
                float c5 = 5.0f * (ex - 1.0f) / (ex + 1.0f);   // 5*tanh(raw/5)
                float val;
                if (i < j)       val = 0.0f;
                else if (i == j) { float z = c5 + 1.0f; val = log1pf(__expf(z)) + 1e-4f; }
                else             val = c5;
                lvp[e] = val;
            }
            *(float4*)&L_s[r][i][j0] = lv;
        }
    }
    __syncthreads();

    // ---- G = L L^T (lower triangle, packed column-major)
    for (int idx = t; idx < RPB * 528; idx += 256) {
        int r  = idx / 528;
        int pr = idx - r * 528;
        int tv = tri_s[pr];
        int i = tv >> 8, j = tv & 255;
        const float* Li = &L_s[r][i][0];
        const float* Lj = &L_s[r][j][0];
        float s = 0.0f;
        int nf = (j + 1) >> 2;
        for (int q = 0; q < nf; ++q) {
            float4 a  = *(const float4*)&Li[q * 4];
            float4 bb = *(const float4*)&Lj[q * 4];
            s += a.x * bb.x + a.y * bb.y + a.z * bb.z + a.w * bb.w;
        }
        for (int tt = nf * 4; tt <= j; ++tt) s = fmaf(Li[tt], Lj[tt], s);
        G_s[r][pr] = s;
    }
    __syncthreads();

    // ---- u = G x
    if (t < RPB * 32) {
        int r = t >> 5, i = t & 31;
        float s = 0.0f;
        #pragma unroll
        for (int j = 0; j < 32; ++j) {
            float gv = (j <= i) ? G_s[r][j * (65 - j) / 2 + i - j]
                                : G_s[r][i * (65 - i) / 2 + j - i];
            s = fmaf(gv, x_s[r][j], s);
        }
        u_s[r][i] = s;
    }
    __syncthreads();

    // ---- c = u . x
    if (t < RPB) {
        float s = 0.0f;
        #pragma unroll
        for (int i = 0; i < 32; ++i) s = fmaf(u_s[t][i], x_s[t][i], s);
        cOut[g0 + t] = s;
    }

    // ---- feature write: quads of 4 bf16, packed uint2 stores (coalesced).
    for (int idx = t; idx < RPB * (KF / 4); idx += 256) {
        int r   = idx / (KF / 4);
        int q   = idx - r * (KF / 4);
        int pos = q * 4;
        int g   = g0 + r;
        bool isA = (g < 1024);
        unsigned short* dst = isA ? (featA + (size_t)g * KF)
                                  : (featB + (size_t)(g - 1024) * KF);
        unsigned short ev[4];
        #pragma unroll
        for (int e = 0; e < 4; ++e) {
            int p = pos + e;
            float va;
            if (p < 1056) {
                int pr = (p < 528) ? p : p - 528;
                bool wantG = (p < 528) ? isA : !isA;
                int tv = tri_s[pr];
                int i = tv >> 8, j = tv & 255;
                float gv = G_s[r][pr] * ((i == j) ? 1.0f : 2.0f);
                float ov = x_s[r][i] * x_s[r][j];
                va = wantG ? gv : ov;
            } else if (p < 1088) {
                int i = p - 1056;
                va = isA ? u_s[r][i] : -2.0f * x_s[r][i];
            } else if (p < 1120) {
                int i = p - 1088;
                va = isA ? x_s[r][i] : -2.0f * u_s[r][i];
            } else {
                va = 0.0f;   // ws re-poisoned 0xAA — pad must be written
            }
            ev[e] = f2bf(va);
        }
        uint2 w;
        w.x = (unsigned)ev[0] | ((unsigned)ev[1] << 16);
        w.y = (unsigned)ev[2] | ((unsigned)ev[3] << 16);
        *(uint2*)(dst + pos) = w;
    }
}

// ---------------------------------------------------------------------------
// K2: out = sqrt(clip(0.5*(cA+cB+A.B))). In-block split-K (verified round-1
// version, unchanged): 256 threads = 4 waves per 32x32 tile; wave w owns
// K-chunk [w*288,(w+1)*288), depth-4 register prefetch, LDS reduction with
// fused epilogue. 512 blocks -> 8 waves/CU. Bijective XCD swizzle.
// ---------------------------------------------------------------------------
__global__ __launch_bounds__(256) void k_gemm(
    const unsigned short* __restrict__ featA,
    const unsigned short* __restrict__ featB,
    const float* __restrict__ cOut,
    float* __restrict__ out)
{
    __shared__ __attribute__((aligned(16))) float red[4][32][36];  // +4 pad

    const int t    = threadIdx.x;
    const int lane = t & 63;
    const int w    = t >> 6;          // wave id 0..3 = K-chunk id

    // bijective XCD swizzle over 512 blocks (512 % 8 == 0)
    const int lin = blockIdx.x;
    const int swz = (lin & 7) * 64 + (lin >> 3);
    const int m0 = (swz & 15) * 32;
    const int n0 = ((swz >> 4) & 15) * 32;
    const int b  = swz >> 8;

    const int fr = lane & 15;
    const int fq = lane >> 4;
    const int kbase = w * 288 + fq * 8;     // this wave's K-chunk start

    const unsigned short* pA0 = featA + (size_t)(b * 512 + n0 + fr) * KF + kbase;
    const unsigned short* pA1 = pA0 + (size_t)16 * KF;
    const unsigned short* pB0 = featB + (size_t)(b * 512 + m0 + fr) * KF + kbase;
    const unsigned short* pB1 = pB0 + (size_t)16 * KF;

    v4f acc00 = {0,0,0,0}, acc01 = {0,0,0,0}, acc10 = {0,0,0,0}, acc11 = {0,0,0,0};

    // depth-4 register prefetch over this wave's 9 k-steps
    uint4 bA0[4], bA1[4], bB0[4], bB1[4];
    #pragma unroll
    for (int s = 0; s < 4; ++s) {
        bA0[s] = *(const uint4*)(pA0 + s * 32);
        bA1[s] = *(const uint4*)(pA1 + s * 32);
        bB0[s] = *(const uint4*)(pB0 + s * 32);
        bB1[s] = *(const uint4*)(pB1 + s * 32);
    }

    #pragma unroll
    for (int s = 0; s < 9; ++s) {
        const int slot = s & 3;
        v8bf a0  = as_v8bf(bA0[slot]);
        v8bf a1  = as_v8bf(bA1[slot]);
        v8bf b0v = as_v8bf(bB0[slot]);
        v8bf b1v = as_v8bf(bB1[slot]);
        const int kn = s + 4;
        if (kn < 9) {
            bA0[slot] = *(const uint4*)(pA0 + kn * 32);
            bA1[slot] = *(const uint4*)(pA1 + kn * 32);
            bB0[slot] = *(const uint4*)(pB0 + kn * 32);
            bB1[slot] = *(const uint4*)(pB1 + kn * 32);
        }
        acc00 = __builtin_amdgcn_mfma_f32_16x16x32_bf16(a0, b0v, acc00, 0, 0, 0);
        acc01 = __builtin_amdgcn_mfma_f32_16x16x32_bf16(a0, b1v, acc01, 0, 0, 0);
        acc10 = __builtin_amdgcn_mfma_f32_16x16x32_bf16(a1, b0v, acc10, 0, 0, 0);
        acc11 = __builtin_amdgcn_mfma_f32_16x16x32_bf16(a1, b1v, acc11, 0, 0, 0);
    }

    // ---- deposit partial tile: D elem (lane,v): row n_l = (lane>>4)*4+v, col m_l = lane&15
    #pragma unroll
    for (int v = 0; v < 4; ++v) {
        red[w][fq * 4 + v][fr]           = acc00[v];
        red[w][fq * 4 + v][fr + 16]      = acc01[v];
        red[w][16 + fq * 4 + v][fr]      = acc10[v];
        red[w][16 + fq * 4 + v][fr + 16] = acc11[v];
    }
    __syncthreads();

    // ---- reduce 4 K-chunks + epilogue. Thread t: row n_l = t>>3, cols m_l0..+3.
    const int n_l  = t >> 3;
    const int m_l0 = (t & 7) * 4;
    float4 s0 = *(const float4*)&red[0][n_l][m_l0];
    float4 s1 = *(const float4*)&red[1][n_l][m_l0];
    float4 s2 = *(const float4*)&red[2][n_l][m_l0];
    float4 s3 = *(const float4*)&red[3][n_l][m_l0];

    const int   n_g = n0 + n_l;
    const float cA  = cOut[b * 512 + n_g];
    const float4 cB = *(const float4*)&cOut[1024 + b * 512 + m0 + m_l0];

    float4 res;
    {
        float tot[4] = { s0.x + s1.x + s2.x + s3.x,
                         s0.y + s1.y + s2.y + s3.y,
                         s0.z + s1.z + s2.z + s3.z,
                         s0.w + s1.w + s2.w + s3.w };
        const float cb[4] = { cB.x, cB.y, cB.z, cB.w };
        float* rp = (float*)&res;
        #pragma unroll
        for (int e = 0; e < 4; ++e) {
            float dsq = 0.5f * (tot[e] + cA + cb[e]);
            dsq = fminf(fmaxf(dsq, 1e-6f), 1e6f);
            rp[e] = sqrtf(dsq);
        }
    }
    *(float4*)&out[((size_t)(b * 512 + n_g)) * 512 + m0 + m_l0] = res;
}

// ---------------------------------------------------------------------------
extern "C" void kernel_launch(void* const* d_in, const int* in_sizes, int n_in,
                              void* d_out, int out_size, void* d_ws, size_t ws_size,
                              hipStream_t stream)
{
    const float* Q  = (const float*)d_in[0];
    const float* K  = (const float*)d_in[1];
    const float* w1 = (const float*)d_in[2];
    const float* b1 = (const float*)d_in[3];
    const float* w2 = (const float*)d_in[4];
    const float* b2 = (const float*)d_in[5];
    float* out = (float*)d_out;

    unsigned short* featA = (unsigned short*)d_ws;            // [1024][1152] bf16
    unsigned short* featB = featA + (size_t)1024 * KF;        // [1024][1152] bf16
    float* cOut = (float*)(featB + (size_t)1024 * KF);        // [2048] fp32

    k_feat<<<dim3(2048 / RPB), dim3(256), 0, stream>>>(Q, K, w1, b1, w2, b2, featA, featB, cOut);
    k_gemm<<<dim3(512), dim3(256), 0, stream>>>(featA, featB, cOut, out);
}